// Round 21
// baseline (268.595 us; speedup 1.0000x reference)
//
#include <hip/hip_runtime.h>
#include <hip/hip_bf16.h>
#include <math.h>

typedef __bf16 bf16_t;
typedef __bf16 bf16x8 __attribute__((ext_vector_type(8)));
typedef __bf16 bf16x4 __attribute__((ext_vector_type(4)));
typedef float  f32x4  __attribute__((ext_vector_type(4)));
typedef long   i64_t;
typedef unsigned long long u64_t;

#define D 768

// ---------------- block reduction helpers (blockDim == 256) ----------------
__device__ inline double blk_sum(double x, double* s) {
#pragma unroll
  for (int m = 32; m; m >>= 1) x += __shfl_xor(x, m);
  __syncthreads();
  if ((threadIdx.x & 63) == 0) s[threadIdx.x >> 6] = x;
  __syncthreads();
  return s[0] + s[1] + s[2] + s[3];
}

// ---------------- block reduction helpers (blockDim == 1024) ---------------
__device__ inline double blk_sum16(double x, double* s) {
#pragma unroll
  for (int m = 32; m; m >>= 1) x += __shfl_xor(x, m);
  __syncthreads();
  if ((threadIdx.x & 63) == 0) s[threadIdx.x >> 6] = x;
  __syncthreads();
  double t = 0.0;
#pragma unroll
  for (int i = 0; i < 16; i++) t += s[i];
  return t;
}

__device__ inline double blk_max16(double x, double* s) {
#pragma unroll
  for (int m = 32; m; m >>= 1) x = fmax(x, __shfl_xor(x, m));
  __syncthreads();
  if ((threadIdx.x & 63) == 0) s[threadIdx.x >> 6] = x;
  __syncthreads();
  double t = s[0];
#pragma unroll
  for (int i = 1; i < 16; i++) t = fmax(t, s[i]);
  return t;
}

// ---------------- K1: fused normalize / quantize prepass --------------------
// Block order (long blocks FIRST to avoid a thin tail):
//   [0, nbW)            W   -> w8t (tile-transposed fp8 x16) + wscale
//   [nbW, +nbT)         T   -> t8T (k-major fp8 x16, [96][1024])
//   [.. , +nbTS)        TS  -> ts_n (f32) + ts_bf (bf16)
//   rest                SUP -> sup_n (f32)
__global__ __launch_bounds__(256) void norm_all(
    const float* __restrict__ Tm, const float* __restrict__ TS,
    const float* __restrict__ SUP, const float* __restrict__ Wm,
    u64_t* __restrict__ t8T, u64_t* __restrict__ w8t,
    float* __restrict__ wscale, float* __restrict__ ts_n,
    bf16_t* __restrict__ ts_bf, float* __restrict__ sup_n,
    double* __restrict__ accd,
    int U, int V, int B, int Q, int nbW, int nbT, int nbTS) {
  const int wave = threadIdx.x >> 6, lane = threadIdx.x & 63;
  const int bid = blockIdx.x;
  if (bid == 0 && threadIdx.x == 0) accd[0] = 0.0;  // zero loss accumulator

  if (bid < nbW) {
    // ---- W: fp8(x16) tile-transposed, coalesced, 4-deep load batching ----
    const int v0 = bid * 64 + wave * 16;  // tile base
    const int r  = lane & 15;
    const int cs = lane >> 4;
    const int v  = v0 + r;
    const bool valid = v < V;
    const float* Wp = Wm + (size_t)v * D;
    u64_t* tile = w8t + (size_t)(v0 >> 4) * 1536;
    const float4 z4 = {0.f, 0.f, 0.f, 0.f};
    float ssf = 0.f;
#pragma unroll
    for (int jb = 0; jb < 6; jb++) {
      float4 x[4], y[4];
#pragma unroll
      for (int u = 0; u < 4; u++) {
        const float* p = Wp + ((jb * 4 + u) * 4 + cs) * 8;
        x[u] = valid ? *(const float4*)p : z4;
        y[u] = valid ? *(const float4*)(p + 4) : z4;
      }
#pragma unroll
      for (int u = 0; u < 4; u++) {
        ssf += x[u].x * x[u].x + x[u].y * x[u].y + x[u].z * x[u].z +
               x[u].w * x[u].w + y[u].x * y[u].x + y[u].y * y[u].y +
               y[u].z * y[u].z + y[u].w * y[u].w;
        int lo = __builtin_amdgcn_cvt_pk_fp8_f32(x[u].x * 16.f, x[u].y * 16.f, 0, false);
        lo = __builtin_amdgcn_cvt_pk_fp8_f32(x[u].z * 16.f, x[u].w * 16.f, lo, true);
        int hi = __builtin_amdgcn_cvt_pk_fp8_f32(y[u].x * 16.f, y[u].y * 16.f, 0, false);
        hi = __builtin_amdgcn_cvt_pk_fp8_f32(y[u].z * 16.f, y[u].w * 16.f, hi, true);
        tile[(jb * 4 + u) * 64 + lane] = ((u64_t)(unsigned)hi << 32) | (unsigned)lo;
      }
    }
    ssf += __shfl_xor(ssf, 16);
    ssf += __shfl_xor(ssf, 32);
    if (cs == 0)
      wscale[v0 + r] = valid
          ? (float)(1.0 / (256.0 * fmax(sqrt((double)ssf), 1e-12)))
          : 0.f;
    return;
  }

  if (bid < nbW + nbT) {  // ---- T: norm + fp8(x16) + transpose -----------
    const int row = (bid - nbW) * 4 + wave;  // 0..1023
    double inv = 0.0;
    if (row < U) {
      const float4* s = (const float4*)(Tm + (size_t)row * D);
      double ss = 0.0;
#pragma unroll
      for (int j = 0; j < 3; j++) {
        float4 v = s[lane + 64 * j];
        ss += (double)v.x * v.x + (double)v.y * v.y +
              (double)v.z * v.z + (double)v.w * v.w;
      }
#pragma unroll
      for (int m = 32; m; m >>= 1) ss += __shfl_xor(ss, m);
      inv = 1.0 / fmax(sqrt(ss), 1e-12);
    }
    const float sc = (float)(inv * 16.0);
#pragma unroll
    for (int h = 0; h < 2; h++) {
      if (h == 1 && lane >= 32) continue;
      const int c = h * 64 + lane;  // chunk 0..95
      u64_t frag = 0ull;
      if (row < U) {
        const float* p = Tm + (size_t)row * D + c * 8;
        float4 x = *(const float4*)p;
        float4 y = *(const float4*)(p + 4);
        int lo = __builtin_amdgcn_cvt_pk_fp8_f32(x.x * sc, x.y * sc, 0, false);
        lo = __builtin_amdgcn_cvt_pk_fp8_f32(x.z * sc, x.w * sc, lo, true);
        int hi = __builtin_amdgcn_cvt_pk_fp8_f32(y.x * sc, y.y * sc, 0, false);
        hi = __builtin_amdgcn_cvt_pk_fp8_f32(y.z * sc, y.w * sc, hi, true);
        frag = ((u64_t)(unsigned)hi << 32) | (unsigned)lo;
      }
      t8T[(size_t)c * 1024 + row] = frag;
    }
    return;
  }

  // ---- TS / SUP: plain L2-normalize ----
  const float* src;
  int row;
  bool is_ts = false;
  if (bid < nbW + nbT + nbTS) { row = (bid - nbW - nbT) * 4 + wave; src = TS; is_ts = true; }
  else                        { row = (bid - nbW - nbT - nbTS) * 4 + wave; src = SUP;
                                if (row >= Q) return; }
  const float4* s = (const float4*)(src + (size_t)row * D);
  float4 v[3];
  double ss = 0.0;
#pragma unroll
  for (int j = 0; j < 3; j++) {
    v[j] = s[lane + 64 * j];
    ss += (double)v[j].x * v[j].x + (double)v[j].y * v[j].y +
          (double)v[j].z * v[j].z + (double)v[j].w * v[j].w;
  }
#pragma unroll
  for (int m = 32; m; m >>= 1) ss += __shfl_xor(ss, m);
  double inv = 1.0 / fmax(sqrt(ss), 1e-12);
  float4 o[3];
#pragma unroll
  for (int j = 0; j < 3; j++) {
    o[j].x = (float)((double)v[j].x * inv);
    o[j].y = (float)((double)v[j].y * inv);
    o[j].z = (float)((double)v[j].z * inv);
    o[j].w = (float)((double)v[j].w * inv);
  }
  float* dst = is_ts ? ts_n : sup_n;
  float* drow = dst + (size_t)row * D;
#pragma unroll
  for (int j = 0; j < 3; j++) ((float4*)drow)[lane + 64 * j] = o[j];
  if (is_ts) {
    bf16_t* brow = ts_bf + (size_t)row * D;
#pragma unroll
    for (int j = 0; j < 3; j++) {
      bf16x4 ob;
      ob[0] = (bf16_t)o[j].x; ob[1] = (bf16_t)o[j].y;
      ob[2] = (bf16_t)o[j].z; ob[3] = (bf16_t)o[j].w;
      *(bf16x4*)(brow + 4 * (lane + 64 * j)) = ob;
    }
  }
}

// ---------------- K2: max-sim GEMM (persistent-T, barrier-free loop) -------
__global__ __launch_bounds__(256) void maxsim_gemm(
    const u64_t* __restrict__ W8T, const u64_t* __restrict__ T8T,
    float* __restrict__ maxpart, int U, int vstride) {
  __shared__ u64_t bt[4 * 96 * 16];  // 48 KB: [subtile][chunk][proto]
  const int tid  = threadIdx.x;
  const int lane = tid & 63;
  const int r    = lane & 15;
  const int ks   = lane >> 4;
  const int g    = blockIdx.x;

  {
    const int pb = g * 64;
#pragma unroll
    for (int j = 0; j < 12; j++) {
      const int m = j * 256 + tid;
      const int s = m / 768;
      const int rem = m - s * 768;
      const int c = rem >> 3, h = rem & 7;
      ulonglong2 val = *(const ulonglong2*)(T8T + (size_t)c * 1024 + pb + s * 16 + h * 2);
      *(ulonglong2*)(bt + s * 1536 + c * 16 + h * 2) = val;
    }
  }
  __syncthreads();

  bool msk[4];
#pragma unroll
  for (int s = 0; s < 4; s++) msk[s] = (g * 64 + s * 16 + r) < U;

  const int wv = tid >> 6;
#pragma unroll
  for (int wt = 0; wt < 4; wt++) {
    const int v0 = blockIdx.y * 256 + wv * 64 + wt * 16;
    const u64_t* ap = W8T + (size_t)(v0 >> 4) * 1536;
    u64_t a[24];
#pragma unroll
    for (int kk = 0; kk < 24; kk++) a[kk] = ap[kk * 64 + lane];
    f32x4 ac0 = {0.f,0.f,0.f,0.f}, ac1 = {0.f,0.f,0.f,0.f};
    f32x4 ac2 = {0.f,0.f,0.f,0.f}, ac3 = {0.f,0.f,0.f,0.f};
#pragma unroll
    for (int kk = 0; kk < 24; kk++) {
      const int ci = kk * 64 + lane;
      ac0 = __builtin_amdgcn_mfma_f32_16x16x32_fp8_fp8(
          (i64_t)a[kk], (i64_t)bt[ci],            ac0, 0, 0, 0);
      ac1 = __builtin_amdgcn_mfma_f32_16x16x32_fp8_fp8(
          (i64_t)a[kk], (i64_t)bt[1536 + ci],     ac1, 0, 0, 0);
      ac2 = __builtin_amdgcn_mfma_f32_16x16x32_fp8_fp8(
          (i64_t)a[kk], (i64_t)bt[2 * 1536 + ci], ac2, 0, 0, 0);
      ac3 = __builtin_amdgcn_mfma_f32_16x16x32_fp8_fp8(
          (i64_t)a[kk], (i64_t)bt[3 * 1536 + ci], ac3, 0, 0, 0);
    }
    f32x4 mx = {-1e30f, -1e30f, -1e30f, -1e30f};
#pragma unroll
    for (int j = 0; j < 4; j++) {
      if (msk[0]) mx[j] = fmaxf(mx[j], ac0[j]);
      if (msk[1]) mx[j] = fmaxf(mx[j], ac1[j]);
      if (msk[2]) mx[j] = fmaxf(mx[j], ac2[j]);
      if (msk[3]) mx[j] = fmaxf(mx[j], ac3[j]);
    }
#pragma unroll
    for (int m = 1; m < 16; m <<= 1) {
#pragma unroll
      for (int j = 0; j < 4; j++) mx[j] = fmaxf(mx[j], __shfl_xor(mx[j], m));
    }
    if (r == 0) {
#pragma unroll
      for (int j = 0; j < 4; j++)
        maxpart[(size_t)g * vstride + v0 + ks * 4 + j] = mx[j];
    }
  }
}

// ---------------- K3: approx sim GEMM (bf16 MFMA) ---------------------------
#define LDSROW 776  // 768 + 8 pad (bf16 units)

__global__ __launch_bounds__(256) void simf_gemm(const float* __restrict__ SUPn,
                                                 const bf16_t* __restrict__ TSb,
                                                 float* __restrict__ sim,
                                                 int Q, int ld, int NTB) {
  __shared__ __align__(16) bf16_t lds[2][16 * LDSROW];
  const int tid  = threadIdx.x;
  const int lane = tid & 63;
  const int rowbase = blockIdx.x * 64 + (tid >> 6) * 16;
  const int arow_i  = rowbase + (lane & 15);

  bf16x8 a[24];
  if (arow_i < Q) {
    const float* ar = SUPn + (size_t)arow_i * D + ((lane >> 4) * 8);
#pragma unroll
    for (int kk = 0; kk < 24; kk++) {
      float4 x = *(const float4*)(ar + kk * 32);
      float4 y = *(const float4*)(ar + kk * 32 + 4);
      bf16x8 f;
      f[0] = (bf16_t)x.x; f[1] = (bf16_t)x.y; f[2] = (bf16_t)x.z; f[3] = (bf16_t)x.w;
      f[4] = (bf16_t)y.x; f[5] = (bf16_t)y.y; f[6] = (bf16_t)y.z; f[7] = (bf16_t)y.w;
      a[kk] = f;
    }
  } else {
#pragma unroll
    for (int kk = 0; kk < 24; kk++) {
      bf16x8 f;
#pragma unroll
      for (int e = 0; e < 8; e++) f[e] = (bf16_t)0.f;
      a[kk] = f;
    }
  }

  auto stage = [&](int buf, int nt) {
    const ulonglong2* src = (const ulonglong2*)(TSb + (size_t)nt * 16 * D);
#pragma unroll
    for (int j = 0; j < 6; j++) {
      int c = tid + j * 256;
      int rr = c / 96, w = c % 96;
      *(ulonglong2*)&lds[buf][rr * LDSROW + w * 8] = src[c];
    }
  };

  stage(0, 0);
  for (int nt = 0; nt < NTB; nt++) {
    __syncthreads();
    if (nt + 1 < NTB) stage((nt + 1) & 1, nt + 1);
    f32x4 acc = {0.f, 0.f, 0.f, 0.f};
    const bf16_t* brow = &lds[nt & 1][(lane & 15) * LDSROW + ((lane >> 4) * 8)];
#pragma unroll
    for (int kk = 0; kk < 24; kk++) {
      bf16x8 b = *(const bf16x8*)(brow + kk * 32);
      acc = __builtin_amdgcn_mfma_f32_16x16x32_bf16(a[kk], b, acc, 0, 0, 0);
    }
    const int bcol = nt * 16 + (lane & 15);
    const int q0   = rowbase + ((lane >> 4) << 2);
    float* dst = sim + (size_t)bcol * ld + q0;
    if (q0 + 3 < Q) {
      *(f32x4*)dst = acc;
    } else {
#pragma unroll
      for (int j = 0; j < 4; j++)
        if (q0 + j < Q) dst[j] = acc[j];
    }
  }
}

// ---------------- K4: top-16 + f64 rescore + gather + pos + NNCL ------------
// 1024 threads/block (16 waves -> 4 waves/SIMD for latency hiding).
__device__ inline unsigned long long pack_key(float v, int q) {
  unsigned u = __float_as_uint(v);
  u = (u & 0x80000000u) ? ~u : (u | 0x80000000u);  // order-preserving map
  return ((unsigned long long)u << 32) | (unsigned)(0xFFFFFFFFu - (unsigned)q);
}

// Merge this lane's sorted-desc top-16 with xor-partner's: top-16 of union
// via max(a[i], partner a[15-i]) (bitonic trick), then 4-stage bitonic
// sort-desc network. All indices compile-time (registers, no scratch).
__device__ inline void kmerge(u64_t* a, int off) {
  u64_t m[16];
#pragma unroll
  for (int i = 0; i < 16; i++) {
    u64_t o = __shfl_xor(a[15 - i], off);
    m[i] = a[i] > o ? a[i] : o;
  }
#pragma unroll
  for (int s = 8; s >= 1; s >>= 1) {
#pragma unroll
    for (int i = 0; i < 16; i++) {
      if ((i & s) == 0) {
        u64_t x = m[i], y = m[i | s];
        m[i]     = x > y ? x : y;
        m[i | s] = x > y ? y : x;
      }
    }
  }
#pragma unroll
  for (int i = 0; i < 16; i++) a[i] = m[i];
}

__global__ __launch_bounds__(1024) void topk_nncl(const float* __restrict__ sim,
                                                  const float* __restrict__ SUPn,
                                                  const float* __restrict__ TSn,
                                                  float* __restrict__ out,
                                                  double* __restrict__ row_loss,
                                                  int Q, int ld, int Bn) {
  __shared__ float tsrow[D];
  __shared__ u64_t wk[16][16];
  __shared__ u64_t merged[16];
  __shared__ double sval[16];
  __shared__ int    sidx[16];
  __shared__ double red[16];
  __shared__ double dotbuf[4][256];
  const int b = blockIdx.x, tid = threadIdx.x;
  const int lane = tid & 63, wv = tid >> 6;  // 16 waves
  if (tid < D) tsrow[tid] = TSn[(size_t)b * D + tid];

  // ---- scan: ~10 grid-stride iterations/thread ----
  const float* row = sim + (size_t)b * ld;
  u64_t best[16];
#pragma unroll
  for (int k = 0; k < 16; k++) best[k] = 0ull;
  for (int q = tid; q < Q; q += 1024) {
    u64_t key = pack_key(row[q], q);
    if (key > best[15]) {
      best[15] = key;
      for (int k = 15; k > 0; k--) {
        if (best[k] > best[k - 1]) {
          u64_t t = best[k]; best[k] = best[k - 1]; best[k - 1] = t;
        } else break;
      }
    }
  }
  // ---- intra-wave butterfly merge (register bitonic) ----
#pragma unroll
  for (int off = 1; off < 64; off <<= 1) kmerge(best, off);
  if (lane == 0) {
#pragma unroll
    for (int k = 0; k < 16; k++) wk[wv][k] = best[k];
  }
  __syncthreads();
  // ---- cross-wave merge: lanes 0..15 of wave 0 ----
  if (wv == 0 && lane < 16) {
    u64_t cur[16];
#pragma unroll
    for (int k = 0; k < 16; k++) cur[k] = wk[lane][k];
#pragma unroll
    for (int off = 1; off < 16; off <<= 1) kmerge(cur, off);
    if (lane == 0) {
#pragma unroll
      for (int k = 0; k < 16; k++) merged[k] = cur[k];
    }
  }
  __syncthreads();

  // ---- exact f64 rescore: candidate wv handled by wave wv (1 round) ----
  {
    int q = (int)(0xFFFFFFFFu - (unsigned)(merged[wv] & 0xFFFFFFFFull));
    const float* sr = SUPn + (size_t)q * D;
    double dot = 0.0;
#pragma unroll
    for (int i = 0; i < 12; i++)
      dot += (double)sr[lane + 64 * i] * (double)tsrow[lane + 64 * i];
#pragma unroll
    for (int m = 32; m; m >>= 1) dot += __shfl_xor(dot, m);
    if (lane == 0) { sval[wv] = dot; sidx[wv] = q; }
  }
  __syncthreads();
  if (tid == 0) {
    for (int i = 1; i < 16; i++) {
      double v = sval[i]; int ix = sidx[i];
      int j = i - 1;
      while (j >= 0 && (sval[j] < v || (sval[j] == v && sidx[j] > ix))) {
        sval[j + 1] = sval[j]; sidx[j + 1] = sidx[j]; j--;
      }
      sval[j + 1] = v; sidx[j + 1] = ix;
    }
  }
  __syncthreads();

  // ---- gather top-8 + positive mean (element e = tid < 768) ----
  float mean = 0.f;
  if (tid < D) {
#pragma unroll
    for (int k = 0; k < 8; k++) {
      float x = SUPn[(size_t)sidx[k] * D + tid];
      out[((size_t)b * 8 + k) * D + tid] = x;
      mean += x;
    }
    mean *= 0.125f;
  }
  double ss = blk_sum16(tid < D ? (double)mean * mean : 0.0, red);
  double inv = 1.0 / fmax(sqrt(ss), 1e-12);
  double dotp = blk_sum16(tid < D ? (double)tsrow[tid] * ((double)mean * inv) : 0.0, red);
  const double p = dotp / (double)0.07f;

  // ---- NNCL: column c = tid&255, D-quarter pt = tid>>8 ----
  {
    const int c = tid & 255, pt = tid >> 8;
    const float* tc = TSn + (size_t)c * D + pt * 192;
    const float* tb = tsrow + pt * 192;
    double d2 = 0.0;
#pragma unroll
    for (int e = 0; e < 192; e += 4) {
      float4 t4 = *(const float4*)(tc + e);
      d2 += (double)tb[e] * t4.x + (double)tb[e + 1] * t4.y +
            (double)tb[e + 2] * t4.z + (double)tb[e + 3] * t4.w;
    }
    dotbuf[pt][c] = d2;
  }
  __syncthreads();
  double logit = -1e300;
  bool diag = false;
  if (tid < 256) {
    diag = (tid == b);
    double d2 = dotbuf[0][tid] + dotbuf[1][tid] + dotbuf[2][tid] + dotbuf[3][tid];
    logit = d2 / (double)0.07f;
  }
  double m = blk_max16((tid < 256 && !diag) ? logit : -1e300, red);
  m = fmax(m, p);
  double term = (tid < 256 && !diag) ? exp(logit - m) : 0.0;
  double ssum = blk_sum16(term, red);
  ssum += exp(p - m);
  if (tid == 0) row_loss[b] = (log(ssum) + m) - p;
  (void)Bn;
}

// ---------------- K5: combine proto maxes -> partial loss sums --------------
__global__ __launch_bounds__(256) void reduce_proto(
    const float* __restrict__ maxpart, const float* __restrict__ wscale,
    double* __restrict__ accd, int V, int vstride) {
  __shared__ double red[4];
  const int v = blockIdx.x * 256 + threadIdx.x;
  double s = 0.0;
  if (v < V) {
    float mx = -1e30f;
#pragma unroll
    for (int g = 0; g < 16; g++)
      mx = fmaxf(mx, maxpart[(size_t)g * vstride + v]);
    s = 2.0 - 2.0 * (double)mx * (double)wscale[v];
  }
  s = blk_sum(s, red);
  if (threadIdx.x == 0) atomicAdd(accd, s);
}

// ---------------- K6: finalize scalars --------------------------------------
__global__ __launch_bounds__(256) void finalize(const double* __restrict__ accd,
                                                const double* __restrict__ row_loss,
                                                float* __restrict__ d_out, int out_size,
                                                int V, int B) {
  __shared__ double red[4];
  const int tid = threadIdx.x;
  double s2 = 0.0;
  for (int b = tid; b < B; b += 256) s2 += row_loss[b];
  s2 = blk_sum(s2, red);
  if (tid == 0) {
    d_out[out_size - 2] = (float)(accd[0] / ((double)V * (double)D));
    d_out[out_size - 1] = (float)(s2 / (double)B);
  }
}

// ---------------- host launcher ---------------------------------------------
extern "C" void kernel_launch(void* const* d_in, const int* in_sizes, int n_in,
                              void* d_out, int out_size, void* d_ws, size_t ws_size,
                              hipStream_t stream) {
  const float* TS  = (const float*)d_in[0];
  const float* W   = (const float*)d_in[1];
  const float* T   = (const float*)d_in[2];
  const float* SUP = (const float*)d_in[3];
  const int B = in_sizes[0] / D;   // 256
  const int V = in_sizes[1] / D;   // 50257
  const int U = in_sizes[2] / D;   // 1000
  const int Q = in_sizes[3] / D;   // 10000
  const int VPAD = (V + 255) & ~255; // 50432
  const int QPAD = (Q + 63) & ~63; // 10048
  const int NTB  = B / 16;         // 16
  const int nbW  = VPAD / 64;      // 788 (long blocks, scheduled first)
  const int nbT  = 1024 / 4;       // 256
  const int nbTS = B / 4;          // 64
  const int nbSUP = (Q + 3) / 4;   // 2500

  char* ws = (char*)d_ws;
  size_t off = 0;
  auto alloc = [&](size_t bytes) -> char* {
    char* p = ws + off;
    off = (off + bytes + 255) & ~(size_t)255;
    return p;
  };
  u64_t*  t8T    = (u64_t*) alloc((size_t)96 * 1024 * 8);
  u64_t*  w8t    = (u64_t*) alloc((size_t)(VPAD / 16) * 1536 * 8);
  float*  wscale = (float*) alloc((size_t)VPAD * 4);
  float*  maxpart= (float*) alloc((size_t)16 * VPAD * 4);
  float*  ts_n   = (float*) alloc((size_t)B * D * 4);
  bf16_t* ts_bf  = (bf16_t*)alloc((size_t)B * D * 2);
  float*  sup_n  = (float*) alloc((size_t)Q * D * 4);
  float*  simf   = (float*) alloc((size_t)B * QPAD * 4);
  double* rloss  = (double*)alloc((size_t)B * 8);
  double* accd   = (double*)alloc(8);
  (void)ws_size; (void)n_in;

  norm_all<<<nbW + nbT + nbTS + nbSUP, 256, 0, stream>>>(
      T, TS, SUP, W, t8T, w8t, wscale, ts_n, ts_bf, sup_n, accd,
      U, V, B, Q, nbW, nbT, nbTS);

  dim3 gms(16, VPAD / 256);
  maxsim_gemm<<<gms, 256, 0, stream>>>(w8t, t8T, maxpart, U, VPAD);

  simf_gemm<<<QPAD / 64, 256, 0, stream>>>(sup_n, ts_bf, simf, Q, QPAD, NTB);
  topk_nncl<<<B, 1024, 0, stream>>>(simf, sup_n, ts_n, (float*)d_out, rloss,
                                    Q, QPAD, B);
  reduce_proto<<<VPAD / 256, 256, 0, stream>>>(maxpart, wscale, accd, V, VPAD);
  finalize<<<1, 256, 0, stream>>>(accd, rloss, (float*)d_out, out_size, V, B);
}

// Round 22
// 211.282 us; speedup vs baseline: 1.2713x; 1.2713x over previous
//
#include <hip/hip_runtime.h>
#include <hip/hip_bf16.h>
#include <math.h>

typedef __bf16 bf16_t;
typedef __bf16 bf16x8 __attribute__((ext_vector_type(8)));
typedef __bf16 bf16x4 __attribute__((ext_vector_type(4)));
typedef float  f32x4  __attribute__((ext_vector_type(4)));
typedef long   i64_t;
typedef unsigned long long u64_t;

#define D 768

// ---------------- block reduction helpers (blockDim == 256) ----------------
__device__ inline double blk_sum(double x, double* s) {
#pragma unroll
  for (int m = 32; m; m >>= 1) x += __shfl_xor(x, m);
  __syncthreads();
  if ((threadIdx.x & 63) == 0) s[threadIdx.x >> 6] = x;
  __syncthreads();
  return s[0] + s[1] + s[2] + s[3];
}

__device__ inline double blk_max(double x, double* s) {
#pragma unroll
  for (int m = 32; m; m >>= 1) x = fmax(x, __shfl_xor(x, m));
  __syncthreads();
  if ((threadIdx.x & 63) == 0) s[threadIdx.x >> 6] = x;
  __syncthreads();
  return fmax(fmax(s[0], s[1]), fmax(s[2], s[3]));
}

// ---------------- K1: fused normalize / quantize prepass --------------------
// Block order (long blocks FIRST to avoid a thin tail):
//   [0, nbW)            W   -> w8t (tile-transposed fp8 x16) + wscale
//   [nbW, +nbT)         T   -> t8T (k-major fp8 x16, [96][1024])
//   [.. , +nbTS)        TS  -> ts_n (f32) + ts_bf (bf16)
//   rest                SUP -> sup_n (f32)
__global__ __launch_bounds__(256) void norm_all(
    const float* __restrict__ Tm, const float* __restrict__ TS,
    const float* __restrict__ SUP, const float* __restrict__ Wm,
    u64_t* __restrict__ t8T, u64_t* __restrict__ w8t,
    float* __restrict__ wscale, float* __restrict__ ts_n,
    bf16_t* __restrict__ ts_bf, float* __restrict__ sup_n,
    double* __restrict__ accd,
    int U, int V, int B, int Q, int nbW, int nbT, int nbTS) {
  const int wave = threadIdx.x >> 6, lane = threadIdx.x & 63;
  const int bid = blockIdx.x;
  if (bid == 0 && threadIdx.x == 0) accd[0] = 0.0;  // zero loss accumulator

  if (bid < nbW) {
    // ---- W: fp8(x16) tile-transposed, coalesced read+write ---------------
    // Wave = one 16-row tile; lane = (cs = lane>>4, r = lane&15).
    // Iter j: read row r chunk c=j*4+cs (32B; 4 lanes/row -> 128B segments),
    // write tile[j*64+lane] (512B coalesced; idx == c*16 + r).
    const int v0 = bid * 64 + wave * 16;  // tile base
    const int r  = lane & 15;
    const int cs = lane >> 4;
    const int v  = v0 + r;
    const bool valid = v < V;
    const float* Wp = Wm + (size_t)v * D;
    u64_t* tile = w8t + (size_t)(v0 >> 4) * 1536;
    float ssf = 0.f;
#pragma unroll
    for (int j = 0; j < 24; j++) {
      u64_t frag = 0ull;
      if (valid) {
        const float* p = Wp + (j * 4 + cs) * 8;
        float4 x = *(const float4*)p;
        float4 y = *(const float4*)(p + 4);
        ssf += x.x * x.x + x.y * x.y + x.z * x.z + x.w * x.w +
               y.x * y.x + y.y * y.y + y.z * y.z + y.w * y.w;
        int lo = __builtin_amdgcn_cvt_pk_fp8_f32(x.x * 16.f, x.y * 16.f, 0, false);
        lo = __builtin_amdgcn_cvt_pk_fp8_f32(x.z * 16.f, x.w * 16.f, lo, true);
        int hi = __builtin_amdgcn_cvt_pk_fp8_f32(y.x * 16.f, y.y * 16.f, 0, false);
        hi = __builtin_amdgcn_cvt_pk_fp8_f32(y.z * 16.f, y.w * 16.f, hi, true);
        frag = ((u64_t)(unsigned)hi << 32) | (unsigned)lo;
      }
      tile[j * 64 + lane] = frag;
    }
    // row-norm: reduce over the 4 lanes sharing r (xor 16, 32)
    ssf += __shfl_xor(ssf, 16);
    ssf += __shfl_xor(ssf, 32);
    if (cs == 0)
      wscale[v0 + r] = valid
          ? (float)(1.0 / (256.0 * fmax(sqrt((double)ssf), 1e-12)))
          : 0.f;
    return;
  }

  if (bid < nbW + nbT) {  // ---- T: norm + fp8(x16) + transpose -----------
    const int row = (bid - nbW) * 4 + wave;  // 0..1023
    double inv = 0.0;
    if (row < U) {
      const float4* s = (const float4*)(Tm + (size_t)row * D);
      double ss = 0.0;
#pragma unroll
      for (int j = 0; j < 3; j++) {
        float4 v = s[lane + 64 * j];
        ss += (double)v.x * v.x + (double)v.y * v.y +
              (double)v.z * v.z + (double)v.w * v.w;
      }
#pragma unroll
      for (int m = 32; m; m >>= 1) ss += __shfl_xor(ss, m);
      inv = 1.0 / fmax(sqrt(ss), 1e-12);
    }
    const float sc = (float)(inv * 16.0);
#pragma unroll
    for (int h = 0; h < 2; h++) {
      if (h == 1 && lane >= 32) continue;
      const int c = h * 64 + lane;  // chunk 0..95
      u64_t frag = 0ull;
      if (row < U) {
        const float* p = Tm + (size_t)row * D + c * 8;
        float4 x = *(const float4*)p;
        float4 y = *(const float4*)(p + 4);
        int lo = __builtin_amdgcn_cvt_pk_fp8_f32(x.x * sc, x.y * sc, 0, false);
        lo = __builtin_amdgcn_cvt_pk_fp8_f32(x.z * sc, x.w * sc, lo, true);
        int hi = __builtin_amdgcn_cvt_pk_fp8_f32(y.x * sc, y.y * sc, 0, false);
        hi = __builtin_amdgcn_cvt_pk_fp8_f32(y.z * sc, y.w * sc, hi, true);
        frag = ((u64_t)(unsigned)hi << 32) | (unsigned)lo;
      }
      t8T[(size_t)c * 1024 + row] = frag;
    }
    return;
  }

  // ---- TS / SUP: plain L2-normalize ----
  const float* src;
  int row;
  bool is_ts = false;
  if (bid < nbW + nbT + nbTS) { row = (bid - nbW - nbT) * 4 + wave; src = TS; is_ts = true; }
  else                        { row = (bid - nbW - nbT - nbTS) * 4 + wave; src = SUP;
                                if (row >= Q) return; }
  const float4* s = (const float4*)(src + (size_t)row * D);
  float4 v[3];
  double ss = 0.0;
#pragma unroll
  for (int j = 0; j < 3; j++) {
    v[j] = s[lane + 64 * j];
    ss += (double)v[j].x * v[j].x + (double)v[j].y * v[j].y +
          (double)v[j].z * v[j].z + (double)v[j].w * v[j].w;
  }
#pragma unroll
  for (int m = 32; m; m >>= 1) ss += __shfl_xor(ss, m);
  double inv = 1.0 / fmax(sqrt(ss), 1e-12);
  float4 o[3];
#pragma unroll
  for (int j = 0; j < 3; j++) {
    o[j].x = (float)((double)v[j].x * inv);
    o[j].y = (float)((double)v[j].y * inv);
    o[j].z = (float)((double)v[j].z * inv);
    o[j].w = (float)((double)v[j].w * inv);
  }
  float* dst = is_ts ? ts_n : sup_n;
  float* drow = dst + (size_t)row * D;
#pragma unroll
  for (int j = 0; j < 3; j++) ((float4*)drow)[lane + 64 * j] = o[j];
  if (is_ts) {
    bf16_t* brow = ts_bf + (size_t)row * D;
#pragma unroll
    for (int j = 0; j < 3; j++) {
      bf16x4 ob;
      ob[0] = (bf16_t)o[j].x; ob[1] = (bf16_t)o[j].y;
      ob[2] = (bf16_t)o[j].z; ob[3] = (bf16_t)o[j].w;
      *(bf16x4*)(brow + 4 * (lane + 64 * j)) = ob;
    }
  }
}

// ---------------- K2: max-sim GEMM (persistent-T, barrier-free loop) -------
__global__ __launch_bounds__(256) void maxsim_gemm(
    const u64_t* __restrict__ W8T, const u64_t* __restrict__ T8T,
    float* __restrict__ maxpart, int U, int vstride) {
  __shared__ u64_t bt[4 * 96 * 16];  // 48 KB: [subtile][chunk][proto]
  const int tid  = threadIdx.x;
  const int lane = tid & 63;
  const int r    = lane & 15;
  const int ks   = lane >> 4;
  const int g    = blockIdx.x;

  {
    const int pb = g * 64;
#pragma unroll
    for (int j = 0; j < 12; j++) {
      const int m = j * 256 + tid;
      const int s = m / 768;
      const int rem = m - s * 768;
      const int c = rem >> 3, h = rem & 7;
      ulonglong2 val = *(const ulonglong2*)(T8T + (size_t)c * 1024 + pb + s * 16 + h * 2);
      *(ulonglong2*)(bt + s * 1536 + c * 16 + h * 2) = val;
    }
  }
  __syncthreads();

  bool msk[4];
#pragma unroll
  for (int s = 0; s < 4; s++) msk[s] = (g * 64 + s * 16 + r) < U;

  const int wv = tid >> 6;
#pragma unroll
  for (int wt = 0; wt < 4; wt++) {
    const int v0 = blockIdx.y * 256 + wv * 64 + wt * 16;
    const u64_t* ap = W8T + (size_t)(v0 >> 4) * 1536;
    u64_t a[24];
#pragma unroll
    for (int kk = 0; kk < 24; kk++) a[kk] = ap[kk * 64 + lane];
    f32x4 ac0 = {0.f,0.f,0.f,0.f}, ac1 = {0.f,0.f,0.f,0.f};
    f32x4 ac2 = {0.f,0.f,0.f,0.f}, ac3 = {0.f,0.f,0.f,0.f};
#pragma unroll
    for (int kk = 0; kk < 24; kk++) {
      const int ci = kk * 64 + lane;
      ac0 = __builtin_amdgcn_mfma_f32_16x16x32_fp8_fp8(
          (i64_t)a[kk], (i64_t)bt[ci],            ac0, 0, 0, 0);
      ac1 = __builtin_amdgcn_mfma_f32_16x16x32_fp8_fp8(
          (i64_t)a[kk], (i64_t)bt[1536 + ci],     ac1, 0, 0, 0);
      ac2 = __builtin_amdgcn_mfma_f32_16x16x32_fp8_fp8(
          (i64_t)a[kk], (i64_t)bt[2 * 1536 + ci], ac2, 0, 0, 0);
      ac3 = __builtin_amdgcn_mfma_f32_16x16x32_fp8_fp8(
          (i64_t)a[kk], (i64_t)bt[3 * 1536 + ci], ac3, 0, 0, 0);
    }
    f32x4 mx = {-1e30f, -1e30f, -1e30f, -1e30f};
#pragma unroll
    for (int j = 0; j < 4; j++) {
      if (msk[0]) mx[j] = fmaxf(mx[j], ac0[j]);
      if (msk[1]) mx[j] = fmaxf(mx[j], ac1[j]);
      if (msk[2]) mx[j] = fmaxf(mx[j], ac2[j]);
      if (msk[3]) mx[j] = fmaxf(mx[j], ac3[j]);
    }
#pragma unroll
    for (int m = 1; m < 16; m <<= 1) {
#pragma unroll
      for (int j = 0; j < 4; j++) mx[j] = fmaxf(mx[j], __shfl_xor(mx[j], m));
    }
    if (r == 0) {
#pragma unroll
      for (int j = 0; j < 4; j++)
        maxpart[(size_t)g * vstride + v0 + ks * 4 + j] = mx[j];
    }
  }
}

// ---------------- K3: approx sim GEMM (bf16 MFMA) ---------------------------
#define LDSROW 776  // 768 + 8 pad (bf16 units)

__global__ __launch_bounds__(256) void simf_gemm(const float* __restrict__ SUPn,
                                                 const bf16_t* __restrict__ TSb,
                                                 float* __restrict__ sim,
                                                 int Q, int ld, int NTB) {
  __shared__ __align__(16) bf16_t lds[2][16 * LDSROW];
  const int tid  = threadIdx.x;
  const int lane = tid & 63;
  const int rowbase = blockIdx.x * 64 + (tid >> 6) * 16;
  const int arow_i  = rowbase + (lane & 15);

  bf16x8 a[24];
  if (arow_i < Q) {
    const float* ar = SUPn + (size_t)arow_i * D + ((lane >> 4) * 8);
#pragma unroll
    for (int kk = 0; kk < 24; kk++) {
      float4 x = *(const float4*)(ar + kk * 32);
      float4 y = *(const float4*)(ar + kk * 32 + 4);
      bf16x8 f;
      f[0] = (bf16_t)x.x; f[1] = (bf16_t)x.y; f[2] = (bf16_t)x.z; f[3] = (bf16_t)x.w;
      f[4] = (bf16_t)y.x; f[5] = (bf16_t)y.y; f[6] = (bf16_t)y.z; f[7] = (bf16_t)y.w;
      a[kk] = f;
    }
  } else {
#pragma unroll
    for (int kk = 0; kk < 24; kk++) {
      bf16x8 f;
#pragma unroll
      for (int e = 0; e < 8; e++) f[e] = (bf16_t)0.f;
      a[kk] = f;
    }
  }

  auto stage = [&](int buf, int nt) {
    const ulonglong2* src = (const ulonglong2*)(TSb + (size_t)nt * 16 * D);
#pragma unroll
    for (int j = 0; j < 6; j++) {
      int c = tid + j * 256;
      int rr = c / 96, w = c % 96;
      *(ulonglong2*)&lds[buf][rr * LDSROW + w * 8] = src[c];
    }
  };

  stage(0, 0);
  for (int nt = 0; nt < NTB; nt++) {
    __syncthreads();
    if (nt + 1 < NTB) stage((nt + 1) & 1, nt + 1);
    f32x4 acc = {0.f, 0.f, 0.f, 0.f};
    const bf16_t* brow = &lds[nt & 1][(lane & 15) * LDSROW + ((lane >> 4) * 8)];
#pragma unroll
    for (int kk = 0; kk < 24; kk++) {
      bf16x8 b = *(const bf16x8*)(brow + kk * 32);
      acc = __builtin_amdgcn_mfma_f32_16x16x32_bf16(a[kk], b, acc, 0, 0, 0);
    }
    const int bcol = nt * 16 + (lane & 15);
    const int q0   = rowbase + ((lane >> 4) << 2);
    float* dst = sim + (size_t)bcol * ld + q0;
    if (q0 + 3 < Q) {
      *(f32x4*)dst = acc;
    } else {
#pragma unroll
      for (int j = 0; j < 4; j++)
        if (q0 + j < Q) dst[j] = acc[j];
    }
  }
}

// ---------------- K4: top-16 + f64 rescore + gather + pos + NNCL -----------
__device__ inline unsigned long long pack_key(float v, int q) {
  unsigned u = __float_as_uint(v);
  u = (u & 0x80000000u) ? ~u : (u | 0x80000000u);  // order-preserving map
  return ((unsigned long long)u << 32) | (unsigned)(0xFFFFFFFFu - (unsigned)q);
}

__global__ __launch_bounds__(256) void topk_nncl(const float* __restrict__ sim,
                                                 const float* __restrict__ SUPn,
                                                 const float* __restrict__ TSn,
                                                 float* __restrict__ out,
                                                 double* __restrict__ row_loss,
                                                 int Q, int ld) {
  __shared__ unsigned long long sk[256][16];
  __shared__ float tsrow[D];
  __shared__ double sval[16];
  __shared__ int    sidx[16];
  __shared__ double red[4];
  const int b = blockIdx.x, tid = threadIdx.x;
#pragma unroll
  for (int j = 0; j < 3; j++) tsrow[tid + 256 * j] = TSn[(size_t)b * D + tid + 256 * j];

  const float* row = sim + (size_t)b * ld;
  unsigned long long best[16];
#pragma unroll
  for (int k = 0; k < 16; k++) best[k] = 0ull;
  for (int q = tid; q < Q; q += 256) {
    unsigned long long key = pack_key(row[q], q);
    if (key > best[15]) {
      best[15] = key;
      for (int k = 15; k > 0; k--) {
        if (best[k] > best[k - 1]) {
          unsigned long long t = best[k]; best[k] = best[k - 1]; best[k - 1] = t;
        } else break;
      }
    }
  }
#pragma unroll
  for (int k = 0; k < 16; k++) sk[tid][k] = best[k];
  for (int stride = 128; stride >= 1; stride >>= 1) {
    __syncthreads();
    if (tid < stride) {
      unsigned long long outk[16];
      int pa = 0, pb = 0;
#pragma unroll
      for (int k = 0; k < 16; k++) {
        unsigned long long va = sk[tid][pa], vb = sk[tid + stride][pb];
        if (va >= vb) { outk[k] = va; pa++; }
        else          { outk[k] = vb; pb++; }
      }
#pragma unroll
      for (int k = 0; k < 16; k++) sk[tid][k] = outk[k];
    }
  }
  __syncthreads();

  // exact f64 rescore of the 16 candidates (1 wave each, 4 rounds)
  const int lane = tid & 63, w = tid >> 6;
  for (int c = w; c < 16; c += 4) {
    int q = (int)(0xFFFFFFFFu - (unsigned)(sk[0][c] & 0xFFFFFFFFull));
    const float* sr = SUPn + (size_t)q * D;
    double dot = 0.0;
#pragma unroll
    for (int i = 0; i < 12; i++)
      dot += (double)sr[lane + 64 * i] * (double)tsrow[lane + 64 * i];
#pragma unroll
    for (int m = 32; m; m >>= 1) dot += __shfl_xor(dot, m);
    if (lane == 0) { sval[c] = dot; sidx[c] = q; }
  }
  __syncthreads();
  if (tid == 0) {
    for (int i = 1; i < 16; i++) {
      double v = sval[i]; int ix = sidx[i];
      int j = i - 1;
      while (j >= 0 && (sval[j] < v || (sval[j] == v && sidx[j] > ix))) {
        sval[j + 1] = sval[j]; sidx[j + 1] = sidx[j]; j--;
      }
      sval[j + 1] = v; sidx[j + 1] = ix;
    }
  }
  __syncthreads();

  // gather top-8 rows to output + positive mean + pos_sim
  float mean[3] = {0.f, 0.f, 0.f};
#pragma unroll
  for (int k = 0; k < 8; k++) {
    const float* sr = SUPn + (size_t)sidx[k] * D;
    float* orow = out + ((size_t)b * 8 + k) * D;
#pragma unroll
    for (int j = 0; j < 3; j++) {
      float x = sr[tid + 256 * j];
      orow[tid + 256 * j] = x;
      mean[j] += x;
    }
  }
#pragma unroll
  for (int j = 0; j < 3; j++) mean[j] *= 0.125f;
  double ss = 0.0;
#pragma unroll
  for (int j = 0; j < 3; j++) ss += (double)mean[j] * mean[j];
  ss = blk_sum(ss, red);
  double inv = 1.0 / fmax(sqrt(ss), 1e-12);
  double dot = 0.0;
#pragma unroll
  for (int j = 0; j < 3; j++)
    dot += (double)tsrow[tid + 256 * j] * ((double)mean[j] * inv);
  dot = blk_sum(dot, red);
  const double p = dot / (double)0.07f;

  // NNCL logsumexp over columns c = tid
  const float* tc = TSn + (size_t)tid * D;
  double dot2 = 0.0;
  for (int e = 0; e < D; e += 4) {
    float4 t4 = *(const float4*)(tc + e);
    dot2 += (double)tsrow[e] * t4.x + (double)tsrow[e + 1] * t4.y +
            (double)tsrow[e + 2] * t4.z + (double)tsrow[e + 3] * t4.w;
  }
  const bool diag = (tid == b);
  double logit = dot2 / (double)0.07f;
  double m = blk_max(diag ? -1e300 : logit, red);
  m = fmax(m, p);
  double term = diag ? 0.0 : exp(logit - m);
  double ssum = blk_sum(term, red);
  ssum += exp(p - m);
  if (tid == 0) row_loss[b] = (log(ssum) + m) - p;
}

// ---------------- K5: combine proto maxes -> partial loss sums --------------
__global__ __launch_bounds__(256) void reduce_proto(
    const float* __restrict__ maxpart, const float* __restrict__ wscale,
    double* __restrict__ accd, int V, int vstride) {
  __shared__ double red[4];
  const int v = blockIdx.x * 256 + threadIdx.x;
  double s = 0.0;
  if (v < V) {
    float mx = -1e30f;
#pragma unroll
    for (int g = 0; g < 16; g++)
      mx = fmaxf(mx, maxpart[(size_t)g * vstride + v]);
    s = 2.0 - 2.0 * (double)mx * (double)wscale[v];
  }
  s = blk_sum(s, red);
  if (threadIdx.x == 0) atomicAdd(accd, s);
}

// ---------------- K6: finalize scalars --------------------------------------
__global__ __launch_bounds__(256) void finalize(const double* __restrict__ accd,
                                                const double* __restrict__ row_loss,
                                                float* __restrict__ d_out, int out_size,
                                                int V, int B) {
  __shared__ double red[4];
  const int tid = threadIdx.x;
  double s2 = 0.0;
  for (int b = tid; b < B; b += 256) s2 += row_loss[b];
  s2 = blk_sum(s2, red);
  if (tid == 0) {
    d_out[out_size - 2] = (float)(accd[0] / ((double)V * (double)D));
    d_out[out_size - 1] = (float)(s2 / (double)B);
  }
}

// ---------------- host launcher ---------------------------------------------
extern "C" void kernel_launch(void* const* d_in, const int* in_sizes, int n_in,
                              void* d_out, int out_size, void* d_ws, size_t ws_size,
                              hipStream_t stream) {
  const float* TS  = (const float*)d_in[0];
  const float* W   = (const float*)d_in[1];
  const float* T   = (const float*)d_in[2];
  const float* SUP = (const float*)d_in[3];
  const int B = in_sizes[0] / D;   // 256
  const int V = in_sizes[1] / D;   // 50257
  const int U = in_sizes[2] / D;   // 1000
  const int Q = in_sizes[3] / D;   // 10000
  const int VPAD = (V + 255) & ~255; // 50432
  const int QPAD = (Q + 63) & ~63; // 10048
  const int NTB  = B / 16;         // 16
  const int nbW  = VPAD / 64;      // 788 (long blocks, scheduled first)
  const int nbT  = 1024 / 4;       // 256
  const int nbTS = B / 4;          // 64
  const int nbSUP = (Q + 3) / 4;   // 2500

  char* ws = (char*)d_ws;
  size_t off = 0;
  auto alloc = [&](size_t bytes) -> char* {
    char* p = ws + off;
    off = (off + bytes + 255) & ~(size_t)255;
    return p;
  };
  u64_t*  t8T    = (u64_t*) alloc((size_t)96 * 1024 * 8);
  u64_t*  w8t    = (u64_t*) alloc((size_t)(VPAD / 16) * 1536 * 8);
  float*  wscale = (float*) alloc((size_t)VPAD * 4);
  float*  maxpart= (float*) alloc((size_t)16 * VPAD * 4);
  float*  ts_n   = (float*) alloc((size_t)B * D * 4);
  bf16_t* ts_bf  = (bf16_t*)alloc((size_t)B * D * 2);
  float*  sup_n  = (float*) alloc((size_t)Q * D * 4);
  float*  simf   = (float*) alloc((size_t)B * QPAD * 4);
  double* rloss  = (double*)alloc((size_t)B * 8);
  double* accd   = (double*)alloc(8);
  (void)ws_size; (void)n_in;

  norm_all<<<nbW + nbT + nbTS + nbSUP, 256, 0, stream>>>(
      T, TS, SUP, W, t8T, w8t, wscale, ts_n, ts_bf, sup_n, accd,
      U, V, B, Q, nbW, nbT, nbTS);

  dim3 gms(16, VPAD / 256);
  maxsim_gemm<<<gms, 256, 0, stream>>>(w8t, t8T, maxpart, U, VPAD);

  simf_gemm<<<QPAD / 64, 256, 0, stream>>>(sup_n, ts_bf, simf, Q, QPAD, NTB);
  topk_nncl<<<B, 256, 0, stream>>>(simf, sup_n, ts_n, (float*)d_out, rloss, Q, QPAD);
  reduce_proto<<<VPAD / 256, 256, 0, stream>>>(maxpart, wscale, accd, V, VPAD);
  finalize<<<1, 256, 0, stream>>>(accd, rloss, (float*)d_out, out_size, V, B);
}

// Round 23
// 194.736 us; speedup vs baseline: 1.3793x; 1.0850x over previous
//
#include <hip/hip_runtime.h>
#include <hip/hip_bf16.h>
#include <math.h>

typedef __bf16 bf16_t;
typedef __bf16 bf16x8 __attribute__((ext_vector_type(8)));
typedef __bf16 bf16x4 __attribute__((ext_vector_type(4)));
typedef float  f32x4  __attribute__((ext_vector_type(4)));
typedef long   i64_t;
typedef unsigned long long u64_t;

#define D 768

// ---------------- block reduction helpers (blockDim == 256) ----------------
__device__ inline double blk_sum(double x, double* s) {
#pragma unroll
  for (int m = 32; m; m >>= 1) x += __shfl_xor(x, m);
  __syncthreads();
  if ((threadIdx.x & 63) == 0) s[threadIdx.x >> 6] = x;
  __syncthreads();
  return s[0] + s[1] + s[2] + s[3];
}

__device__ inline double blk_max(double x, double* s) {
#pragma unroll
  for (int m = 32; m; m >>= 1) x = fmax(x, __shfl_xor(x, m));
  __syncthreads();
  if ((threadIdx.x & 63) == 0) s[threadIdx.x >> 6] = x;
  __syncthreads();
  return fmax(fmax(s[0], s[1]), fmax(s[2], s[3]));
}

// ---------------- K1: normalize T (fp8 k-major), TS, SUP --------------------
//   [0, nbT)        T   -> t8T (k-major fp8 x16, [96][1024])
//   [nbT, +nbTS)    TS  -> ts_n (f32) + ts_bf (bf16)
//   rest            SUP -> sup_n (f32)
__global__ __launch_bounds__(256) void norm_rest(
    const float* __restrict__ Tm, const float* __restrict__ TS,
    const float* __restrict__ SUP, u64_t* __restrict__ t8T,
    float* __restrict__ ts_n, bf16_t* __restrict__ ts_bf,
    float* __restrict__ sup_n, double* __restrict__ accd,
    int U, int B, int Q, int nbT, int nbTS) {
  const int wave = threadIdx.x >> 6, lane = threadIdx.x & 63;
  const int bid = blockIdx.x;
  if (bid == 0 && threadIdx.x == 0) accd[0] = 0.0;  // zero loss accumulator

  if (bid < nbT) {  // ---- T: norm + fp8(x16) + transpose to [96][1024] ----
    const int row = bid * 4 + wave;  // 0..1023
    double inv = 0.0;
    if (row < U) {
      const float4* s = (const float4*)(Tm + (size_t)row * D);
      double ss = 0.0;
#pragma unroll
      for (int j = 0; j < 3; j++) {
        float4 v = s[lane + 64 * j];
        ss += (double)v.x * v.x + (double)v.y * v.y +
              (double)v.z * v.z + (double)v.w * v.w;
      }
#pragma unroll
      for (int m = 32; m; m >>= 1) ss += __shfl_xor(ss, m);
      inv = 1.0 / fmax(sqrt(ss), 1e-12);
    }
    const float sc = (float)(inv * 16.0);
#pragma unroll
    for (int h = 0; h < 2; h++) {
      if (h == 1 && lane >= 32) continue;
      const int c = h * 64 + lane;  // chunk 0..95
      u64_t frag = 0ull;
      if (row < U) {
        const float* p = Tm + (size_t)row * D + c * 8;
        float4 x = *(const float4*)p;
        float4 y = *(const float4*)(p + 4);
        int lo = __builtin_amdgcn_cvt_pk_fp8_f32(x.x * sc, x.y * sc, 0, false);
        lo = __builtin_amdgcn_cvt_pk_fp8_f32(x.z * sc, x.w * sc, lo, true);
        int hi = __builtin_amdgcn_cvt_pk_fp8_f32(y.x * sc, y.y * sc, 0, false);
        hi = __builtin_amdgcn_cvt_pk_fp8_f32(y.z * sc, y.w * sc, hi, true);
        frag = ((u64_t)(unsigned)hi << 32) | (unsigned)lo;
      }
      t8T[(size_t)c * 1024 + row] = frag;
    }
    return;
  }

  // ---- TS / SUP: plain L2-normalize ----
  const float* src;
  int row;
  bool is_ts = false;
  if (bid < nbT + nbTS) { row = (bid - nbT) * 4 + wave; src = TS; is_ts = true; }
  else                  { row = (bid - nbT - nbTS) * 4 + wave; src = SUP;
                          if (row >= Q) return; }
  const float4* s = (const float4*)(src + (size_t)row * D);
  float4 v[3];
  double ss = 0.0;
#pragma unroll
  for (int j = 0; j < 3; j++) {
    v[j] = s[lane + 64 * j];
    ss += (double)v[j].x * v[j].x + (double)v[j].y * v[j].y +
          (double)v[j].z * v[j].z + (double)v[j].w * v[j].w;
  }
#pragma unroll
  for (int m = 32; m; m >>= 1) ss += __shfl_xor(ss, m);
  double inv = 1.0 / fmax(sqrt(ss), 1e-12);
  float4 o[3];
#pragma unroll
  for (int j = 0; j < 3; j++) {
    o[j].x = (float)((double)v[j].x * inv);
    o[j].y = (float)((double)v[j].y * inv);
    o[j].z = (float)((double)v[j].z * inv);
    o[j].w = (float)((double)v[j].w * inv);
  }
  float* dst = is_ts ? ts_n : sup_n;
  float* drow = dst + (size_t)row * D;
#pragma unroll
  for (int j = 0; j < 3; j++) ((float4*)drow)[lane + 64 * j] = o[j];
  if (is_ts) {
    bf16_t* brow = ts_bf + (size_t)row * D;
#pragma unroll
    for (int j = 0; j < 3; j++) {
      bf16x4 ob;
      ob[0] = (bf16_t)o[j].x; ob[1] = (bf16_t)o[j].y;
      ob[2] = (bf16_t)o[j].z; ob[3] = (bf16_t)o[j].w;
      *(bf16x4*)(brow + 4 * (lane + 64 * j)) = ob;
    }
  }
}

// ---------------- K2: approx sim GEMM (bf16 MFMA) ---------------------------
#define LDSROW 776  // 768 + 8 pad (bf16 units)

__global__ __launch_bounds__(256) void simf_gemm(const float* __restrict__ SUPn,
                                                 const bf16_t* __restrict__ TSb,
                                                 float* __restrict__ sim,
                                                 int Q, int ld, int NTB) {
  __shared__ __align__(16) bf16_t lds[2][16 * LDSROW];
  const int tid  = threadIdx.x;
  const int lane = tid & 63;
  const int rowbase = blockIdx.x * 64 + (tid >> 6) * 16;
  const int arow_i  = rowbase + (lane & 15);

  bf16x8 a[24];
  if (arow_i < Q) {
    const float* ar = SUPn + (size_t)arow_i * D + ((lane >> 4) * 8);
#pragma unroll
    for (int kk = 0; kk < 24; kk++) {
      float4 x = *(const float4*)(ar + kk * 32);
      float4 y = *(const float4*)(ar + kk * 32 + 4);
      bf16x8 f;
      f[0] = (bf16_t)x.x; f[1] = (bf16_t)x.y; f[2] = (bf16_t)x.z; f[3] = (bf16_t)x.w;
      f[4] = (bf16_t)y.x; f[5] = (bf16_t)y.y; f[6] = (bf16_t)y.z; f[7] = (bf16_t)y.w;
      a[kk] = f;
    }
  } else {
#pragma unroll
    for (int kk = 0; kk < 24; kk++) {
      bf16x8 f;
#pragma unroll
      for (int e = 0; e < 8; e++) f[e] = (bf16_t)0.f;
      a[kk] = f;
    }
  }

  auto stage = [&](int buf, int nt) {
    const ulonglong2* src = (const ulonglong2*)(TSb + (size_t)nt * 16 * D);
#pragma unroll
    for (int j = 0; j < 6; j++) {
      int c = tid + j * 256;
      int rr = c / 96, w = c % 96;
      *(ulonglong2*)&lds[buf][rr * LDSROW + w * 8] = src[c];
    }
  };

  stage(0, 0);
  for (int nt = 0; nt < NTB; nt++) {
    __syncthreads();
    if (nt + 1 < NTB) stage((nt + 1) & 1, nt + 1);
    f32x4 acc = {0.f, 0.f, 0.f, 0.f};
    const bf16_t* brow = &lds[nt & 1][(lane & 15) * LDSROW + ((lane >> 4) * 8)];
#pragma unroll
    for (int kk = 0; kk < 24; kk++) {
      bf16x8 b = *(const bf16x8*)(brow + kk * 32);
      acc = __builtin_amdgcn_mfma_f32_16x16x32_bf16(a[kk], b, acc, 0, 0, 0);
    }
    const int bcol = nt * 16 + (lane & 15);
    const int q0   = rowbase + ((lane >> 4) << 2);
    float* dst = sim + (size_t)bcol * ld + q0;
    if (q0 + 3 < Q) {
      *(f32x4*)dst = acc;
    } else {
#pragma unroll
      for (int j = 0; j < 4; j++)
        if (q0 + j < Q) dst[j] = acc[j];
    }
  }
}

// ---------------- K3: FUSED topk_nncl (blocks 0..255) + W-quant (rest) ------
// topk blocks are latency-bound (1/CU); W-quant blocks are bandwidth-bound
// and fill the remaining CU slots -> the two ~100us phases co-schedule.
__device__ inline unsigned long long pack_key(float v, int q) {
  unsigned u = __float_as_uint(v);
  u = (u & 0x80000000u) ? ~u : (u | 0x80000000u);  // order-preserving map
  return ((unsigned long long)u << 32) | (unsigned)(0xFFFFFFFFu - (unsigned)q);
}

__global__ __launch_bounds__(256) void fused_topk_wquant(
    const float* __restrict__ sim, const float* __restrict__ SUPn,
    const float* __restrict__ TSn, const float* __restrict__ Wm,
    u64_t* __restrict__ w8t, float* __restrict__ wscale,
    float* __restrict__ out, double* __restrict__ row_loss,
    int Q, int ld, int V, int nbTopk) {
  __shared__ unsigned long long sk[256][16];
  __shared__ float tsrow[D];
  __shared__ double sval[16];
  __shared__ int    sidx[16];
  __shared__ double red[4];
  const int tid = threadIdx.x;

  if (blockIdx.x >= nbTopk) {
    // ---- W: fp8(x16) tile-transposed, coalesced read+write (r22 body) ----
    const int wave = tid >> 6, lane = tid & 63;
    const int v0 = (blockIdx.x - nbTopk) * 64 + wave * 16;  // tile base
    const int r  = lane & 15;
    const int cs = lane >> 4;
    const int v  = v0 + r;
    const bool valid = v < V;
    const float* Wp = Wm + (size_t)v * D;
    u64_t* tile = w8t + (size_t)(v0 >> 4) * 1536;
    float ssf = 0.f;
#pragma unroll
    for (int j = 0; j < 24; j++) {
      u64_t frag = 0ull;
      if (valid) {
        const float* p = Wp + (j * 4 + cs) * 8;
        float4 x = *(const float4*)p;
        float4 y = *(const float4*)(p + 4);
        ssf += x.x * x.x + x.y * x.y + x.z * x.z + x.w * x.w +
               y.x * y.x + y.y * y.y + y.z * y.z + y.w * y.w;
        int lo = __builtin_amdgcn_cvt_pk_fp8_f32(x.x * 16.f, x.y * 16.f, 0, false);
        lo = __builtin_amdgcn_cvt_pk_fp8_f32(x.z * 16.f, x.w * 16.f, lo, true);
        int hi = __builtin_amdgcn_cvt_pk_fp8_f32(y.x * 16.f, y.y * 16.f, 0, false);
        hi = __builtin_amdgcn_cvt_pk_fp8_f32(y.z * 16.f, y.w * 16.f, hi, true);
        frag = ((u64_t)(unsigned)hi << 32) | (unsigned)lo;
      }
      tile[j * 64 + lane] = frag;
    }
    ssf += __shfl_xor(ssf, 16);
    ssf += __shfl_xor(ssf, 32);
    if (cs == 0)
      wscale[v0 + r] = valid
          ? (float)(1.0 / (256.0 * fmax(sqrt((double)ssf), 1e-12)))
          : 0.f;
    return;
  }

  // ---- topk_nncl body (r22, byte-identical logic; b = blockIdx.x) ----
  const int b = blockIdx.x;
#pragma unroll
  for (int j = 0; j < 3; j++) tsrow[tid + 256 * j] = TSn[(size_t)b * D + tid + 256 * j];

  const float* row = sim + (size_t)b * ld;
  unsigned long long best[16];
#pragma unroll
  for (int k = 0; k < 16; k++) best[k] = 0ull;
  for (int q = tid; q < Q; q += 256) {
    unsigned long long key = pack_key(row[q], q);
    if (key > best[15]) {
      best[15] = key;
      for (int k = 15; k > 0; k--) {
        if (best[k] > best[k - 1]) {
          unsigned long long t = best[k]; best[k] = best[k - 1]; best[k - 1] = t;
        } else break;
      }
    }
  }
#pragma unroll
  for (int k = 0; k < 16; k++) sk[tid][k] = best[k];
  for (int stride = 128; stride >= 1; stride >>= 1) {
    __syncthreads();
    if (tid < stride) {
      unsigned long long outk[16];
      int pa = 0, pb = 0;
#pragma unroll
      for (int k = 0; k < 16; k++) {
        unsigned long long va = sk[tid][pa], vb = sk[tid + stride][pb];
        if (va >= vb) { outk[k] = va; pa++; }
        else          { outk[k] = vb; pb++; }
      }
#pragma unroll
      for (int k = 0; k < 16; k++) sk[tid][k] = outk[k];
    }
  }
  __syncthreads();

  // exact f64 rescore of the 16 candidates (1 wave each, 4 rounds)
  const int lane = tid & 63, w = tid >> 6;
  for (int c = w; c < 16; c += 4) {
    int q = (int)(0xFFFFFFFFu - (unsigned)(sk[0][c] & 0xFFFFFFFFull));
    const float* sr = SUPn + (size_t)q * D;
    double dot = 0.0;
#pragma unroll
    for (int i = 0; i < 12; i++)
      dot += (double)sr[lane + 64 * i] * (double)tsrow[lane + 64 * i];
#pragma unroll
    for (int m = 32; m; m >>= 1) dot += __shfl_xor(dot, m);
    if (lane == 0) { sval[c] = dot; sidx[c] = q; }
  }
  __syncthreads();
  if (tid == 0) {
    for (int i = 1; i < 16; i++) {
      double v = sval[i]; int ix = sidx[i];
      int j = i - 1;
      while (j >= 0 && (sval[j] < v || (sval[j] == v && sidx[j] > ix))) {
        sval[j + 1] = sval[j]; sidx[j + 1] = sidx[j]; j--;
      }
      sval[j + 1] = v; sidx[j + 1] = ix;
    }
  }
  __syncthreads();

  // gather top-8 rows to output + positive mean + pos_sim
  float mean[3] = {0.f, 0.f, 0.f};
#pragma unroll
  for (int k = 0; k < 8; k++) {
    const float* sr = SUPn + (size_t)sidx[k] * D;
    float* orow = out + ((size_t)b * 8 + k) * D;
#pragma unroll
    for (int j = 0; j < 3; j++) {
      float x = sr[tid + 256 * j];
      orow[tid + 256 * j] = x;
      mean[j] += x;
    }
  }
#pragma unroll
  for (int j = 0; j < 3; j++) mean[j] *= 0.125f;
  double ss = 0.0;
#pragma unroll
  for (int j = 0; j < 3; j++) ss += (double)mean[j] * mean[j];
  ss = blk_sum(ss, red);
  double inv = 1.0 / fmax(sqrt(ss), 1e-12);
  double dot = 0.0;
#pragma unroll
  for (int j = 0; j < 3; j++)
    dot += (double)tsrow[tid + 256 * j] * ((double)mean[j] * inv);
  dot = blk_sum(dot, red);
  const double p = dot / (double)0.07f;

  // NNCL logsumexp over columns c = tid
  const float* tc = TSn + (size_t)tid * D;
  double dot2 = 0.0;
  for (int e = 0; e < D; e += 4) {
    float4 t4 = *(const float4*)(tc + e);
    dot2 += (double)tsrow[e] * t4.x + (double)tsrow[e + 1] * t4.y +
            (double)tsrow[e + 2] * t4.z + (double)tsrow[e + 3] * t4.w;
  }
  const bool diag = (tid == b);
  double logit = dot2 / (double)0.07f;
  double m = blk_max(diag ? -1e300 : logit, red);
  m = fmax(m, p);
  double term = diag ? 0.0 : exp(logit - m);
  double ssum = blk_sum(term, red);
  ssum += exp(p - m);
  if (tid == 0) row_loss[b] = (log(ssum) + m) - p;
}

// ---------------- K4: max-sim GEMM (persistent-T, barrier-free loop) -------
__global__ __launch_bounds__(256) void maxsim_gemm(
    const u64_t* __restrict__ W8T, const u64_t* __restrict__ T8T,
    float* __restrict__ maxpart, int U, int vstride) {
  __shared__ u64_t bt[4 * 96 * 16];  // 48 KB: [subtile][chunk][proto]
  const int tid  = threadIdx.x;
  const int lane = tid & 63;
  const int r    = lane & 15;
  const int ks   = lane >> 4;
  const int g    = blockIdx.x;

  {
    const int pb = g * 64;
#pragma unroll
    for (int j = 0; j < 12; j++) {
      const int m = j * 256 + tid;
      const int s = m / 768;
      const int rem = m - s * 768;
      const int c = rem >> 3, h = rem & 7;
      ulonglong2 val = *(const ulonglong2*)(T8T + (size_t)c * 1024 + pb + s * 16 + h * 2);
      *(ulonglong2*)(bt + s * 1536 + c * 16 + h * 2) = val;
    }
  }
  __syncthreads();

  bool msk[4];
#pragma unroll
  for (int s = 0; s < 4; s++) msk[s] = (g * 64 + s * 16 + r) < U;

  const int wv = tid >> 6;
#pragma unroll
  for (int wt = 0; wt < 4; wt++) {
    const int v0 = blockIdx.y * 256 + wv * 64 + wt * 16;
    const u64_t* ap = W8T + (size_t)(v0 >> 4) * 1536;
    u64_t a[24];
#pragma unroll
    for (int kk = 0; kk < 24; kk++) a[kk] = ap[kk * 64 + lane];
    f32x4 ac0 = {0.f,0.f,0.f,0.f}, ac1 = {0.f,0.f,0.f,0.f};
    f32x4 ac2 = {0.f,0.f,0.f,0.f}, ac3 = {0.f,0.f,0.f,0.f};
#pragma unroll
    for (int kk = 0; kk < 24; kk++) {
      const int ci = kk * 64 + lane;
      ac0 = __builtin_amdgcn_mfma_f32_16x16x32_fp8_fp8(
          (i64_t)a[kk], (i64_t)bt[ci],            ac0, 0, 0, 0);
      ac1 = __builtin_amdgcn_mfma_f32_16x16x32_fp8_fp8(
          (i64_t)a[kk], (i64_t)bt[1536 + ci],     ac1, 0, 0, 0);
      ac2 = __builtin_amdgcn_mfma_f32_16x16x32_fp8_fp8(
          (i64_t)a[kk], (i64_t)bt[2 * 1536 + ci], ac2, 0, 0, 0);
      ac3 = __builtin_amdgcn_mfma_f32_16x16x32_fp8_fp8(
          (i64_t)a[kk], (i64_t)bt[3 * 1536 + ci], ac3, 0, 0, 0);
    }
    f32x4 mx = {-1e30f, -1e30f, -1e30f, -1e30f};
#pragma unroll
    for (int j = 0; j < 4; j++) {
      if (msk[0]) mx[j] = fmaxf(mx[j], ac0[j]);
      if (msk[1]) mx[j] = fmaxf(mx[j], ac1[j]);
      if (msk[2]) mx[j] = fmaxf(mx[j], ac2[j]);
      if (msk[3]) mx[j] = fmaxf(mx[j], ac3[j]);
    }
#pragma unroll
    for (int m = 1; m < 16; m <<= 1) {
#pragma unroll
      for (int j = 0; j < 4; j++) mx[j] = fmaxf(mx[j], __shfl_xor(mx[j], m));
    }
    if (r == 0) {
#pragma unroll
      for (int j = 0; j < 4; j++)
        maxpart[(size_t)g * vstride + v0 + ks * 4 + j] = mx[j];
    }
  }
}

// ---------------- K5: combine proto maxes -> partial loss sums --------------
__global__ __launch_bounds__(256) void reduce_proto(
    const float* __restrict__ maxpart, const float* __restrict__ wscale,
    double* __restrict__ accd, int V, int vstride) {
  __shared__ double red[4];
  const int v = blockIdx.x * 256 + threadIdx.x;
  double s = 0.0;
  if (v < V) {
    float mx = -1e30f;
#pragma unroll
    for (int g = 0; g < 16; g++)
      mx = fmaxf(mx, maxpart[(size_t)g * vstride + v]);
    s = 2.0 - 2.0 * (double)mx * (double)wscale[v];
  }
  s = blk_sum(s, red);
  if (threadIdx.x == 0) atomicAdd(accd, s);
}

// ---------------- K6: finalize scalars --------------------------------------
__global__ __launch_bounds__(256) void finalize(const double* __restrict__ accd,
                                                const double* __restrict__ row_loss,
                                                float* __restrict__ d_out, int out_size,
                                                int V, int B) {
  __shared__ double red[4];
  const int tid = threadIdx.x;
  double s2 = 0.0;
  for (int b = tid; b < B; b += 256) s2 += row_loss[b];
  s2 = blk_sum(s2, red);
  if (tid == 0) {
    d_out[out_size - 2] = (float)(accd[0] / ((double)V * (double)D));
    d_out[out_size - 1] = (float)(s2 / (double)B);
  }
}

// ---------------- host launcher ---------------------------------------------
extern "C" void kernel_launch(void* const* d_in, const int* in_sizes, int n_in,
                              void* d_out, int out_size, void* d_ws, size_t ws_size,
                              hipStream_t stream) {
  const float* TS  = (const float*)d_in[0];
  const float* W   = (const float*)d_in[1];
  const float* T   = (const float*)d_in[2];
  const float* SUP = (const float*)d_in[3];
  const int B = in_sizes[0] / D;   // 256
  const int V = in_sizes[1] / D;   // 50257
  const int U = in_sizes[2] / D;   // 1000
  const int Q = in_sizes[3] / D;   // 10000
  const int VPAD = (V + 255) & ~255; // 50432
  const int QPAD = (Q + 63) & ~63; // 10048
  const int NTB  = B / 16;         // 16
  const int nbW  = VPAD / 64;      // 788
  const int nbT  = 1024 / 4;       // 256
  const int nbTS = B / 4;          // 64
  const int nbSUP = (Q + 3) / 4;   // 2500

  char* ws = (char*)d_ws;
  size_t off = 0;
  auto alloc = [&](size_t bytes) -> char* {
    char* p = ws + off;
    off = (off + bytes + 255) & ~(size_t)255;
    return p;
  };
  u64_t*  t8T    = (u64_t*) alloc((size_t)96 * 1024 * 8);
  u64_t*  w8t    = (u64_t*) alloc((size_t)(VPAD / 16) * 1536 * 8);
  float*  wscale = (float*) alloc((size_t)VPAD * 4);
  float*  maxpart= (float*) alloc((size_t)16 * VPAD * 4);
  float*  ts_n   = (float*) alloc((size_t)B * D * 4);
  bf16_t* ts_bf  = (bf16_t*)alloc((size_t)B * D * 2);
  float*  sup_n  = (float*) alloc((size_t)Q * D * 4);
  float*  simf   = (float*) alloc((size_t)B * QPAD * 4);
  double* rloss  = (double*)alloc((size_t)B * 8);
  double* accd   = (double*)alloc(8);
  (void)ws_size; (void)n_in;

  norm_rest<<<nbT + nbTS + nbSUP, 256, 0, stream>>>(
      T, TS, SUP, t8T, ts_n, ts_bf, sup_n, accd, U, B, Q, nbT, nbTS);

  simf_gemm<<<QPAD / 64, 256, 0, stream>>>(sup_n, ts_bf, simf, Q, QPAD, NTB);

  fused_topk_wquant<<<B + nbW, 256, 0, stream>>>(
      simf, sup_n, ts_n, W, w8t, wscale, (float*)d_out, rloss, Q, QPAD, V, B);

  dim3 gms(16, VPAD / 256);
  maxsim_gemm<<<gms, 256, 0, stream>>>(w8t, t8T, maxpart, U, VPAD);

  reduce_proto<<<VPAD / 256, 256, 0, stream>>>(maxpart, wscale, accd, V, VPAD);
  finalize<<<1, 256, 0, stream>>>(accd, rloss, (float*)d_out, out_size, V, B);
}